// Round 11
// baseline (240.369 us; speedup 1.0000x reference)
//
#include <hip/hip_runtime.h>
#include <hip/hip_bf16.h>
#include <cstdint>

#define T_TOK 8192
#define HID   1024
#define NE    9      // 8 routed experts + 1 shared
#define ISZ   512
#define RBASE 18432  // routed slots: 16384 + 8*256 pad; shared rows at [RBASE, RBASE+8192)
#define NSLOT (RBASE + T_TOK)   // 26624

#define BM 256
#define BN 128
#define BK 64
#define NROWB (NSLOT / BM)      // 104  (divisible by 8)
#define NCOLB (HID / BN)        // 8

typedef unsigned short u16;
typedef unsigned int   u32;
typedef __attribute__((ext_vector_type(8))) short short8;
typedef __attribute__((ext_vector_type(4))) float f32x4;

__device__ __forceinline__ u16 f2bf(float f) {
  u32 u = __builtin_bit_cast(u32, f);
  return (u16)((u + 0x7fffu + ((u >> 16) & 1u)) >> 16);
}
__device__ __forceinline__ float bf2f(u16 v) {
  return __builtin_bit_cast(float, (u32)v << 16);
}

#define STAGE(gp, lp) __builtin_amdgcn_global_load_lds( \
    (__attribute__((address_space(1))) u32*)(gp),       \
    (__attribute__((address_space(3))) u32*)(lp), 16, 0, 0)

// ---------------- k_prep: cvt_wgup + cvt_wdown + router in ONE launch ----------
#define NB_WGUP (32 * 32 * NE)   // 9216
#define NB_WDN  (32 * 16 * NE)   // 4608
#define NB_RTR  (T_TOK / 4)      // 2048

__global__ __launch_bounds__(256) void k_prep(
    const float* __restrict__ x, const float* __restrict__ wg,
    const float* __restrict__ wgu, const float* __restrict__ wsg,
    const float* __restrict__ wdn, const float* __restrict__ wsd,
    u16* __restrict__ xb, u16* __restrict__ wgupT, u16* __restrict__ wdT,
    int* __restrict__ eidx, float2* __restrict__ wts) {
  __shared__ float tile[32][33];
  const int b = blockIdx.x;
  const int tid = threadIdx.x;

  if (b < NB_WGUP) {
    const int e = b / 1024, rem = b % 1024;
    const int c0 = (rem & 31) * 32, h0 = (rem >> 5) * 32;
    const float* src = (e < 8) ? (wgu + (size_t)e * HID * 1024) : wsg;
    const int tx = tid & 31, ty = tid >> 5;
    for (int i = ty; i < 32; i += 8)
      tile[i][tx] = src[(size_t)(h0 + i) * 1024 + c0 + tx];
    __syncthreads();
    for (int j = ty; j < 32; j += 8) {
      int c = c0 + j;
      int i = (c < 512) ? c : (c - 512);
      int colp = ((i >> 4) * 32) + ((c < 512) ? 0 : 16) + (i & 15);
      wgupT[((size_t)e * 1024 + colp) * HID + h0 + tx] = f2bf(tile[tx][j]);
    }
    return;
  }
  if (b < NB_WGUP + NB_WDN) {
    const int bb = b - NB_WGUP;
    const int e = bb / 512, rem = bb % 512;
    const int h0 = (rem & 31) * 32, i0 = (rem >> 5) * 32;
    const float* src = (e < 8) ? (wdn + (size_t)e * ISZ * HID) : wsd;
    const int tx = tid & 31, ty = tid >> 5;
    for (int a = ty; a < 32; a += 8)
      tile[a][tx] = src[(size_t)(i0 + a) * HID + h0 + tx];
    __syncthreads();
    for (int j = ty; j < 32; j += 8)
      wdT[((size_t)e * HID + h0 + j) * ISZ + i0 + tx] = f2bf(tile[tx][j]);
    return;
  }
  const int t = (b - NB_WGUP - NB_WDN) * 4 + (tid >> 6);
  const int l = tid & 63;
  float a[8] = {0, 0, 0, 0, 0, 0, 0, 0};
  const float4* xr4 = (const float4*)(x + (size_t)t * HID);
  ushort4* xb4 = (ushort4*)(xb + (size_t)t * HID);
#pragma unroll
  for (int j = 0; j < 4; ++j) {
    const float4 v = xr4[j * 64 + l];
    ushort4 o;
    o.x = f2bf(v.x); o.y = f2bf(v.y); o.z = f2bf(v.z); o.w = f2bf(v.w);
    xb4[j * 64 + l] = o;
    const int h = (j * 64 + l) * 4;
    const float ev[4] = {v.x, v.y, v.z, v.w};
#pragma unroll
    for (int i = 0; i < 4; ++i) {
      const float4 w0 = *(const float4*)&wg[(h + i) * 8];
      const float4 w1 = *(const float4*)&wg[(h + i) * 8 + 4];
      a[0] += ev[i] * w0.x; a[1] += ev[i] * w0.y; a[2] += ev[i] * w0.z; a[3] += ev[i] * w0.w;
      a[4] += ev[i] * w1.x; a[5] += ev[i] * w1.y; a[6] += ev[i] * w1.z; a[7] += ev[i] * w1.w;
    }
  }
#pragma unroll
  for (int off = 32; off >= 1; off >>= 1) {
#pragma unroll
    for (int e2 = 0; e2 < 8; ++e2) a[e2] += __shfl_xor(a[e2], off);
  }
  if (l == 0) {
    int ia = 0;
#pragma unroll
    for (int e2 = 1; e2 < 8; ++e2) if (a[e2] > a[ia]) ia = e2;
    int ib = (ia == 0) ? 1 : 0;
#pragma unroll
    for (int e2 = 0; e2 < 8; ++e2) if (e2 != ia && a[e2] > a[ib]) ib = e2;
    float wa = 1.f / (1.f + expf(a[ib] - a[ia]));
    eidx[t] = ia | (ib << 8);
    wts[t] = make_float2(wa, 1.f - wa);
  }
}

// ---------------- deterministic counting scatter (256-aligned segments) --------
__global__ __launch_bounds__(512) void k_scatter(
    const int* __restrict__ eidx, int* __restrict__ btok, int* __restrict__ slotmap,
    int* __restrict__ seg, int* __restrict__ segcnt) {
  __shared__ int cnt_s[8];
  __shared__ int goff_s[9];
  const int e = threadIdx.x >> 6;
  const int l = threadIdx.x & 63;

  int c1 = 0;
  for (int c = 0; c < T_TOK / 64; ++c) {
    int v = eidx[c * 64 + l];
    c1 += __popcll(__ballot((v & 255) == e)) + __popcll(__ballot(((v >> 8) & 255) == e));
  }
  if (l == 0) cnt_s[e] = c1;
  __syncthreads();
  if (threadIdx.x == 0) {
    int off = 0;
    for (int k = 0; k < 8; ++k) { goff_s[k] = off; off += (cnt_s[k] + 255) & ~255; }
    goff_s[8] = off;
  }
  __syncthreads();
  const int base0 = goff_s[e];
  const int cnt_e = cnt_s[e];
  const unsigned long long below = (l == 63) ? ~0ull >> 1 : ((1ull << l) - 1);

  int base = base0;
  for (int c = 0; c < T_TOK / 64; ++c) {
    const int t = c * 64 + l;
    const int v = eidx[t];
    const unsigned long long ma = __ballot((v & 255) == e);
    const unsigned long long mb = __ballot(((v >> 8) & 255) == e);
    if ((v & 255) == e) {
      int s = base + __popcll(ma & below);
      btok[s] = t; slotmap[2 * t] = s;
    }
    if (((v >> 8) & 255) == e) {
      int s = base + __popcll(ma) + __popcll(mb & below);
      btok[s] = t; slotmap[2 * t + 1] = s;
    }
    base += __popcll(ma) + __popcll(mb);
  }
  for (int p = cnt_e + l; p < ((cnt_e + 255) & ~255); p += 64) btok[base0 + p] = 0;
  if (threadIdx.x < 9) seg[threadIdx.x] = goff_s[threadIdx.x];
  if (threadIdx.x < 8) segcnt[threadIdx.x] = cnt_s[threadIdx.x];
}

__device__ __forceinline__ bool seg_lookup(const int* __restrict__ seg,
                                           const int* __restrict__ segcnt,
                                           int brow, int& e) {
  if (brow >= RBASE) { e = 8; return true; }
  if (brow >= seg[8]) return false;
  e = 0;
#pragma unroll
  for (int k = 1; k < 8; ++k) if (brow >= seg[k]) e = k;
  return brow < seg[e] + segcnt[e];
}

// =================================================================================
// 256x128 tile, BK=64 slots, 8 waves 4M x 2N (per-wave 64x64, acc[4][4]).
// LDS: 3-ring (A 3x32KB, B 3x16KB = 144 KB). Stage slot s+2 during s; slot-end
// counted vmcnt(6) (never drained mid-loop). Per slot: issue BOTH kk frag sets
// (16 ds_read_b128), lgkmcnt(8) -> 16 MFMA (kk0) while kk1 reads drain ->
// lgkmcnt(0) -> 16 MFMA (kk1). One barrier per slot. ^(row&7) swizzle both sides
// (r9-verified: 0 bank conflicts). XCD grouping: row-panel pinned to one XCD.
// =================================================================================

#define STG1(kt) do { const int _r = ((kt) % 3) * 16384;            \
    STAGE(sA0 + (kt) * BK, As + _r + 0 * 4096 + w * 512);           \
    STAGE(sA1 + (kt) * BK, As + _r + 1 * 4096 + w * 512);           \
    STAGE(sA2 + (kt) * BK, As + _r + 2 * 4096 + w * 512);           \
    STAGE(sA3 + (kt) * BK, As + _r + 3 * 4096 + w * 512);           \
    const int _rb = ((kt) % 3) * 8192;                              \
    STAGE(sB0 + (kt) * BK, Bs + _rb + 0 * 4096 + w * 512);          \
    STAGE(sB1 + (kt) * BK, Bs + _rb + 1 * 4096 + w * 512); } while (0)

#define LOADF(SA, SB, RG, KX) do {                                  \
    _Pragma("unroll") for (int m = 0; m < 4; ++m)                   \
      SA[m] = *(const short8*)&As[(RG) * 16384 + aBase + m * 1024 + (KX)]; \
    _Pragma("unroll") for (int n = 0; n < 4; ++n)                   \
      SB[n] = *(const short8*)&Bs[(RG) * 8192 + bBase + n * 1024 + (KX)]; } while (0)

#define MFMA16(SA, SB) do { __builtin_amdgcn_s_setprio(1);          \
    _Pragma("unroll") for (int m = 0; m < 4; ++m)                   \
      _Pragma("unroll") for (int n = 0; n < 4; ++n)                 \
        acc[m][n] = __builtin_amdgcn_mfma_f32_16x16x32_bf16(SA[m], SB[n], acc[m][n], 0, 0, 0); \
    __builtin_amdgcn_s_setprio(0); } while (0)

#define GEMM_PIPE(NKT)                                              \
  STG1(0); STG1(1);                                                 \
  asm volatile("s_waitcnt vmcnt(6)" ::: "memory");                  \
  __builtin_amdgcn_s_barrier();                                     \
  for (int s = 0; s < (NKT); ++s) {                                 \
    const int rg = s % 3;                                           \
    if (s + 2 < (NKT)) STG1(s + 2);                                 \
    LOADF(fA0, fB0, rg, kx0);                                       \
    __builtin_amdgcn_sched_barrier(0);                              \
    LOADF(fA1, fB1, rg, kx1);                                       \
    asm volatile("s_waitcnt lgkmcnt(8)" ::: "memory");              \
    __builtin_amdgcn_sched_barrier(0);                              \
    MFMA16(fA0, fB0);                                               \
    asm volatile("s_waitcnt lgkmcnt(0)" ::: "memory");              \
    __builtin_amdgcn_sched_barrier(0);                              \
    MFMA16(fA1, fB1);                                               \
    if (s + 1 < (NKT)) {                                            \
      if (s + 2 < (NKT)) { asm volatile("s_waitcnt vmcnt(6)" ::: "memory"); } \
      else               { asm volatile("s_waitcnt vmcnt(0)" ::: "memory"); } \
      __builtin_amdgcn_s_barrier();                                 \
    }                                                               \
  }

// ---------------- GEMM1: act[slot] = silu(g)*u  (A gathered by token) -----------
__global__ __launch_bounds__(512) void k_gemm_gu(
    const u16* __restrict__ xb,     // [T][H] bf16
    const u16* __restrict__ wgupT,  // [NE][1024][H] bf16 (B^T, gate/up interleaved)
    const int* __restrict__ seg, const int* __restrict__ segcnt,
    const int* __restrict__ btok,
    u16* __restrict__ act)          // [NSLOT][ISZ] bf16
{
  // XCD grouping: rb % 8 == blockIdx.x % 8 -> one row-panel's 8 col-tiles on 1 XCD
  const int xg = blockIdx.x & 7, q = blockIdx.x >> 3;
  const int rb = xg + 8 * (q >> 3);
  const int cb = q & 7;
  const int brow = rb * BM, bcol = cb * BN;
  int e;
  if (!seg_lookup(seg, segcnt, brow, e)) return;

  __shared__ __align__(16) u16 As[3 * 16384];  // 96 KB
  __shared__ __align__(16) u16 Bs[3 * 8192];   // 48 KB

  const int tid = threadIdx.x;
  const int w = tid >> 6, l = tid & 63;
  const int wm = w >> 1, wn = w & 1;           // 4M x 2N
  const int fr = l & 15, fg = l >> 4;

  // staging: per instr j, rows j*64 + w*8 + (l>>3); source chunk pre-swizzled
  const int rr = w * 8 + (l >> 3);
  const int sw = ((l & 7) ^ (l >> 3)) * 8;
  int tr[4];
#pragma unroll
  for (int j = 0; j < 4; ++j) {
    const int gr = brow + j * 64 + rr;
    tr[j] = (e < 8) ? btok[gr] : (gr - RBASE);
  }
  const u16* sA0 = xb + (size_t)tr[0] * HID + sw;
  const u16* sA1 = xb + (size_t)tr[1] * HID + sw;
  const u16* sA2 = xb + (size_t)tr[2] * HID + sw;
  const u16* sA3 = xb + (size_t)tr[3] * HID + sw;
  const u16* sB0 = wgupT + ((size_t)e * 1024 + bcol + 0 * 64 + rr) * HID + sw;
  const u16* sB1 = wgupT + ((size_t)e * 1024 + bcol + 1 * 64 + rr) * HID + sw;

  // frag read geometry: row*64 elems + swizzled chunk
  const int aBase = (wm * 64 + fr) * 64;
  const int bBase = (wn * 64 + fr) * 64;
  const int kx0 = (fg ^ (fr & 7)) * 8;
  const int kx1 = kx0 ^ 32;

  f32x4 acc[4][4];
#pragma unroll
  for (int m = 0; m < 4; ++m)
#pragma unroll
    for (int n = 0; n < 4; ++n) acc[m][n] = (f32x4){0.f, 0.f, 0.f, 0.f};
  short8 fA0[4], fB0[4], fA1[4], fB1[4];

  GEMM_PIPE(HID / BK)   // 16 slots

  // epilogue: n pairs (2p, 2p+1) = (gate, up)
#pragma unroll
  for (int m = 0; m < 4; ++m) {
#pragma unroll
    for (int p = 0; p < 2; ++p) {
      f32x4 g = acc[m][2 * p], u = acc[m][2 * p + 1];
      const int col = ((bcol + wn * 64) >> 1) + p * 16 + fr;
#pragma unroll
      for (int r = 0; r < 4; ++r) {
        const int row_l = wm * 64 + m * 16 + fg * 4 + r;
        float gate = g[r];
        float sv = gate / (1.f + __expf(-gate));
        act[(size_t)(brow + row_l) * ISZ + col] = f2bf(sv * u[r]);
      }
    }
  }
}

// ---------------- GEMM2: tmp[slot] = act[slot] @ wdT[e] -------------------------
__global__ __launch_bounds__(512) void k_gemm_down(
    const u16* __restrict__ act, const u16* __restrict__ wdT,
    const int* __restrict__ seg, const int* __restrict__ segcnt,
    u16* __restrict__ tmp) {
  const int xg = blockIdx.x & 7, q = blockIdx.x >> 3;
  const int rb = xg + 8 * (q >> 3);
  const int cb = q & 7;
  const int brow = rb * BM, bcol = cb * BN;
  int e;
  if (!seg_lookup(seg, segcnt, brow, e)) return;

  __shared__ __align__(16) u16 As[3 * 16384];
  __shared__ __align__(16) u16 Bs[3 * 8192];

  const int tid = threadIdx.x;
  const int w = tid >> 6, l = tid & 63;
  const int wm = w >> 1, wn = w & 1;
  const int fr = l & 15, fg = l >> 4;

  const int rr = w * 8 + (l >> 3);
  const int sw = ((l & 7) ^ (l >> 3)) * 8;
  const u16* sA0 = act + (size_t)(brow + 0 * 64 + rr) * ISZ + sw;
  const u16* sA1 = act + (size_t)(brow + 1 * 64 + rr) * ISZ + sw;
  const u16* sA2 = act + (size_t)(brow + 2 * 64 + rr) * ISZ + sw;
  const u16* sA3 = act + (size_t)(brow + 3 * 64 + rr) * ISZ + sw;
  const u16* sB0 = wdT + ((size_t)e * 1024 + bcol + 0 * 64 + rr) * ISZ + sw;
  const u16* sB1 = wdT + ((size_t)e * 1024 + bcol + 1 * 64 + rr) * ISZ + sw;

  const int aBase = (wm * 64 + fr) * 64;
  const int bBase = (wn * 64 + fr) * 64;
  const int kx0 = (fg ^ (fr & 7)) * 8;
  const int kx1 = kx0 ^ 32;

  f32x4 acc[4][4];
#pragma unroll
  for (int m = 0; m < 4; ++m)
#pragma unroll
    for (int n = 0; n < 4; ++n) acc[m][n] = (f32x4){0.f, 0.f, 0.f, 0.f};
  short8 fA0[4], fB0[4], fA1[4], fB1[4];

  GEMM_PIPE(ISZ / BK)   // 8 slots

#pragma unroll
  for (int m = 0; m < 4; ++m) {
#pragma unroll
    for (int r = 0; r < 4; ++r) {
      const int row = brow + wm * 64 + m * 16 + fg * 4 + r;
#pragma unroll
      for (int n = 0; n < 4; ++n) {
        const int col = bcol + wn * 64 + n * 16 + fr;
        tmp[(size_t)row * HID + col] = f2bf(acc[m][n][r]);
      }
    }
  }
}

// ---------------- combine: out[t] = tmp[sh] + w0*tmp[s0] + w1*tmp[s1] -----------
__global__ __launch_bounds__(256) void k_combine(
    const u16* __restrict__ tmp, const int* __restrict__ slotmap,
    const float2* __restrict__ wts, float* __restrict__ out) {
  const int idx = blockIdx.x * 256 + threadIdx.x;
  const int t = idx >> 7;
  const int c = (idx & 127) << 3;
  const int s0 = slotmap[2 * t], s1 = slotmap[2 * t + 1];
  const float2 wv = wts[t];
  const short8 a = *(const short8*)(tmp + (size_t)s0 * HID + c);
  const short8 b = *(const short8*)(tmp + (size_t)s1 * HID + c);
  const short8 s = *(const short8*)(tmp + (size_t)(RBASE + t) * HID + c);
  float r[8];
#pragma unroll
  for (int j = 0; j < 8; ++j)
    r[j] = bf2f((u16)s[j]) + wv.x * bf2f((u16)a[j]) + wv.y * bf2f((u16)b[j]);
  float* po = out + (size_t)t * HID + c;
  *(float4*)po       = make_float4(r[0], r[1], r[2], r[3]);
  *(float4*)(po + 4) = make_float4(r[4], r[5], r[6], r[7]);
}

// ---------------- launch ----------------
extern "C" void kernel_launch(void* const* d_in, const int* in_sizes, int n_in,
                              void* d_out, int out_size, void* d_ws, size_t ws_size,
                              hipStream_t stream) {
  const float* x   = (const float*)d_in[0];
  const float* wg  = (const float*)d_in[1];
  const float* wgu = (const float*)d_in[2];
  const float* wdn = (const float*)d_in[3];
  const float* wsg = (const float*)d_in[4];
  const float* wsd = (const float*)d_in[5];
  float* out = (float*)d_out;

  char* ws = (char*)d_ws;
  u16* xb    = (u16*)ws;  ws += (size_t)T_TOK * HID * 2;
  u16* wgupT = (u16*)ws;  ws += (size_t)NE * 1024 * HID * 2;
  u16* wdT   = (u16*)ws;  ws += (size_t)NE * HID * ISZ * 2;
  u16* actb  = (u16*)ws;  ws += (size_t)NSLOT * ISZ * 2;
  u16* tmp   = (u16*)ws;  ws += (size_t)NSLOT * HID * 2;
  int* eidx  = (int*)ws;  ws += (size_t)T_TOK * 4;
  float2* wt = (float2*)ws; ws += (size_t)T_TOK * 8;
  int* btok  = (int*)ws;  ws += (size_t)RBASE * 4;
  int* smap  = (int*)ws;  ws += (size_t)2 * T_TOK * 4;
  int* seg   = (int*)ws;  ws += 16 * 4;
  int* segc  = (int*)ws;

  k_prep<<<NB_WGUP + NB_WDN + NB_RTR, 256, 0, stream>>>(
      x, wg, wgu, wsg, wdn, wsd, xb, wgupT, wdT, eidx, wt);
  k_scatter<<<1, 512, 0, stream>>>(eidx, btok, smap, seg, segc);
  k_gemm_gu<<<NROWB * NCOLB, 512, 0, stream>>>(
      xb, wgupT, seg, segc, btok, actb);
  k_gemm_down<<<NROWB * NCOLB, 512, 0, stream>>>(actb, wdT, seg, segc, tmp);
  k_combine<<<(T_TOK * HID / 8) / 256, 256, 0, stream>>>(tmp, smap, wt, out);
}

// Round 12
// 213.500 us; speedup vs baseline: 1.1259x; 1.1259x over previous
//
#include <hip/hip_runtime.h>
#include <hip/hip_bf16.h>
#include <cstdint>

#define T_TOK 8192
#define HID   1024
#define NE    9
#define ISZ   512
#define RBASE 18432
#define NSLOT (RBASE + T_TOK)   // 26624

#define BM 256
#define NROWB (NSLOT / BM)      // 104

typedef unsigned short u16;
typedef unsigned int   u32;
typedef signed char    i8;
typedef __attribute__((ext_vector_type(8))) short short8;
typedef __attribute__((ext_vector_type(4))) float f32x4;
typedef __attribute__((ext_vector_type(4))) int   i32x4;

__device__ __forceinline__ u16 f2bf(float f) {
  u32 u = __builtin_bit_cast(u32, f);
  return (u16)((u + 0x7fffu + ((u >> 16) & 1u)) >> 16);
}
__device__ __forceinline__ float bf2f(u16 v) {
  return __builtin_bit_cast(float, (u32)v << 16);
}
__device__ __forceinline__ int q8(float v, float inv) {
  int q = (int)__builtin_rintf(v * inv);
  return (q > 127) ? 127 : ((q < -127) ? -127 : q);
}

#define STAGE(gp, lp) __builtin_amdgcn_global_load_lds( \
    (__attribute__((address_space(1))) u32*)(gp),       \
    (__attribute__((address_space(3))) u32*)(lp), 16, 0, 0)

// ---------------- zero init for wamax ----------------
__global__ void k_zero(int* wam) { if (threadIdx.x < 16) wam[threadIdx.x] = 0; }

// ---------------- per-expert weight amax (gate_up) ----------------
__global__ __launch_bounds__(256) void k_wamax(
    const float* __restrict__ wgu, const float* __restrict__ wsg, int* __restrict__ wam) {
  const int e = blockIdx.y;
  const float* src = (e < 8) ? (wgu + (size_t)e * 1048576) : wsg;
  float m = 0.f;
  for (int i = blockIdx.x * 256 + threadIdx.x; i < 262144; i += 16 * 256) {
    float4 v = ((const float4*)src)[i];
    m = fmaxf(m, fmaxf(fmaxf(fabsf(v.x), fabsf(v.y)), fmaxf(fabsf(v.z), fabsf(v.w))));
  }
#pragma unroll
  for (int off = 32; off >= 1; off >>= 1) m = fmaxf(m, __shfl_xor(m, off));
  __shared__ float sm[4];
  if ((threadIdx.x & 63) == 0) sm[threadIdx.x >> 6] = m;
  __syncthreads();
  if (threadIdx.x == 0) {
    m = fmaxf(fmaxf(sm[0], sm[1]), fmaxf(sm[2], sm[3]));
    atomicMax(wam + e, __float_as_int(m));
  }
}

// ---------------- k_prep: wgup->i8(transposed,interleaved), wdn->bf16T, router+x-quant
#define NB_WGUP (32 * 32 * NE)   // 9216
#define NB_WDN  (32 * 16 * NE)   // 4608
#define NB_RTR  (T_TOK / 4)      // 2048

__global__ __launch_bounds__(256) void k_prep(
    const float* __restrict__ x, const float* __restrict__ wg,
    const float* __restrict__ wgu, const float* __restrict__ wsg,
    const float* __restrict__ wdn, const float* __restrict__ wsd,
    const int* __restrict__ wam,
    i8* __restrict__ xq, float* __restrict__ sxg,
    i8* __restrict__ wguq, u16* __restrict__ wdT,
    int* __restrict__ eidx, float2* __restrict__ wts) {
  __shared__ float tile[32][33];
  const int b = blockIdx.x;
  const int tid = threadIdx.x;

  if (b < NB_WGUP) {
    const int e = b / 1024, rem = b % 1024;
    const int c0 = (rem & 31) * 32, h0 = (rem >> 5) * 32;
    const float* src = (e < 8) ? (wgu + (size_t)e * HID * 1024) : wsg;
    const float invw = 127.f / __int_as_float(wam[e]);
    const int tx = tid & 31, ty = tid >> 5;
    for (int i = ty; i < 32; i += 8)
      tile[i][tx] = src[(size_t)(h0 + i) * 1024 + c0 + tx];
    __syncthreads();
    for (int j = ty; j < 32; j += 8) {
      int c = c0 + j;
      int i = (c < 512) ? c : (c - 512);
      int colp = ((i >> 4) * 32) + ((c < 512) ? 0 : 16) + (i & 15);
      wguq[((size_t)e * 1024 + colp) * HID + h0 + tx] = (i8)q8(tile[tx][j], invw);
    }
    return;
  }
  if (b < NB_WGUP + NB_WDN) {
    const int bb = b - NB_WGUP;
    const int e = bb / 512, rem = bb % 512;
    const int h0 = (rem & 31) * 32, i0 = (rem >> 5) * 32;
    const float* src = (e < 8) ? (wdn + (size_t)e * ISZ * HID) : wsd;
    const int tx = tid & 31, ty = tid >> 5;
    for (int a = ty; a < 32; a += 8)
      tile[a][tx] = src[(size_t)(i0 + a) * HID + h0 + tx];
    __syncthreads();
    for (int j = ty; j < 32; j += 8)
      wdT[((size_t)e * HID + h0 + j) * ISZ + i0 + tx] = f2bf(tile[tx][j]);
    return;
  }
  // router: 4 tokens/block; fused per-row amax quant of x
  const int t = (b - NB_WGUP - NB_WDN) * 4 + (tid >> 6);
  const int l = tid & 63;
  float a[8] = {0, 0, 0, 0, 0, 0, 0, 0};
  float vals[16];
  float am = 0.f;
  const float4* xr4 = (const float4*)(x + (size_t)t * HID);
#pragma unroll
  for (int j = 0; j < 4; ++j) {
    const float4 v = xr4[j * 64 + l];
    vals[4 * j] = v.x; vals[4 * j + 1] = v.y; vals[4 * j + 2] = v.z; vals[4 * j + 3] = v.w;
    am = fmaxf(am, fmaxf(fmaxf(fabsf(v.x), fabsf(v.y)), fmaxf(fabsf(v.z), fabsf(v.w))));
    const int h = (j * 64 + l) * 4;
#pragma unroll
    for (int i = 0; i < 4; ++i) {
      const float4 w0 = *(const float4*)&wg[(h + i) * 8];
      const float4 w1 = *(const float4*)&wg[(h + i) * 8 + 4];
      const float ev = vals[4 * j + i];
      a[0] += ev * w0.x; a[1] += ev * w0.y; a[2] += ev * w0.z; a[3] += ev * w0.w;
      a[4] += ev * w1.x; a[5] += ev * w1.y; a[6] += ev * w1.z; a[7] += ev * w1.w;
    }
  }
#pragma unroll
  for (int off = 32; off >= 1; off >>= 1) {
    am = fmaxf(am, __shfl_xor(am, off));
#pragma unroll
    for (int e2 = 0; e2 < 8; ++e2) a[e2] += __shfl_xor(a[e2], off);
  }
  const float inv = (am > 0.f) ? 127.f / am : 0.f;
  u32* xq4 = (u32*)(xq + (size_t)t * HID);
#pragma unroll
  for (int j = 0; j < 4; ++j) {
    u32 q = ((u32)(unsigned char)(i8)q8(vals[4 * j], inv)) |
            ((u32)(unsigned char)(i8)q8(vals[4 * j + 1], inv) << 8) |
            ((u32)(unsigned char)(i8)q8(vals[4 * j + 2], inv) << 16) |
            ((u32)(unsigned char)(i8)q8(vals[4 * j + 3], inv) << 24);
    xq4[j * 64 + l] = q;
  }
  if (l == 0) {
    sxg[t] = am * (1.f / 127.f);
    int ia = 0;
#pragma unroll
    for (int e2 = 1; e2 < 8; ++e2) if (a[e2] > a[ia]) ia = e2;
    int ib = (ia == 0) ? 1 : 0;
#pragma unroll
    for (int e2 = 0; e2 < 8; ++e2) if (e2 != ia && a[e2] > a[ib]) ib = e2;
    float wa = 1.f / (1.f + expf(a[ib] - a[ia]));
    eidx[t] = ia | (ib << 8);
    wts[t] = make_float2(wa, 1.f - wa);
  }
}

// ---------------- deterministic counting scatter (256-aligned segments) --------
__global__ __launch_bounds__(512) void k_scatter(
    const int* __restrict__ eidx, int* __restrict__ btok, int* __restrict__ slotmap,
    int* __restrict__ seg, int* __restrict__ segcnt) {
  __shared__ int cnt_s[8];
  __shared__ int goff_s[9];
  const int e = threadIdx.x >> 6;
  const int l = threadIdx.x & 63;

  int c1 = 0;
  for (int c = 0; c < T_TOK / 64; ++c) {
    int v = eidx[c * 64 + l];
    c1 += __popcll(__ballot((v & 255) == e)) + __popcll(__ballot(((v >> 8) & 255) == e));
  }
  if (l == 0) cnt_s[e] = c1;
  __syncthreads();
  if (threadIdx.x == 0) {
    int off = 0;
    for (int k = 0; k < 8; ++k) { goff_s[k] = off; off += (cnt_s[k] + 255) & ~255; }
    goff_s[8] = off;
  }
  __syncthreads();
  const int base0 = goff_s[e];
  const int cnt_e = cnt_s[e];
  const unsigned long long below = (l == 63) ? ~0ull >> 1 : ((1ull << l) - 1);

  int base = base0;
  for (int c = 0; c < T_TOK / 64; ++c) {
    const int t = c * 64 + l;
    const int v = eidx[t];
    const unsigned long long ma = __ballot((v & 255) == e);
    const unsigned long long mb = __ballot(((v >> 8) & 255) == e);
    if ((v & 255) == e) {
      int s = base + __popcll(ma & below);
      btok[s] = t; slotmap[2 * t] = s;
    }
    if (((v >> 8) & 255) == e) {
      int s = base + __popcll(ma) + __popcll(mb & below);
      btok[s] = t; slotmap[2 * t + 1] = s;
    }
    base += __popcll(ma) + __popcll(mb);
  }
  for (int p = cnt_e + l; p < ((cnt_e + 255) & ~255); p += 64) btok[base0 + p] = 0;
  if (threadIdx.x < 9) seg[threadIdx.x] = goff_s[threadIdx.x];
  if (threadIdx.x < 8) segcnt[threadIdx.x] = cnt_s[threadIdx.x];
}

__device__ __forceinline__ bool seg_lookup(const int* __restrict__ seg,
                                           const int* __restrict__ segcnt,
                                           int brow, int& e) {
  if (brow >= RBASE) { e = 8; return true; }
  if (brow >= seg[8]) return false;
  e = 0;
#pragma unroll
  for (int k = 1; k < 8; ++k) if (brow >= seg[k]) e = k;
  return brow < seg[e] + segcnt[e];
}

// =================================================================================
// GEMM1 (int8): 256x128 tile, K-slot=128 i8 (128-B rows), 8 waves 4M x 2N (64x64).
// LDS 3-ring: A 3x32KB + B 3x16KB = 144 KB. Stage slot s+2 during s; counted
// vmcnt(6); per slot 16 ds_read_b128, lgkm(8) -> 16 MFMA -> lgkm(0) -> 16 MFMA.
// ^(row&7) 16B-chunk swizzle both sides (r11-verified: 0 bank conflicts).
// mfma_i32_16x16x64_i8; dequant sx[row]*sw[e] in epilogue before silu.
// =================================================================================

#define G1_STG(kt) do {                                             \
    const int _ra = ((kt) % 3) * 32768;                             \
    STAGE(sA0 + (kt) * 128, Ab + _ra + 0 * 8192 + w * 1024);        \
    STAGE(sA1 + (kt) * 128, Ab + _ra + 1 * 8192 + w * 1024);        \
    STAGE(sA2 + (kt) * 128, Ab + _ra + 2 * 8192 + w * 1024);        \
    STAGE(sA3 + (kt) * 128, Ab + _ra + 3 * 8192 + w * 1024);        \
    const int _rb = ((kt) % 3) * 16384;                             \
    STAGE(sB0 + (kt) * 128, Bb + _rb + 0 * 8192 + w * 1024);        \
    STAGE(sB1 + (kt) * 128, Bb + _rb + 1 * 8192 + w * 1024); } while (0)

#define G1_LOADF(SA, SB, RG, KX) do {                               \
    _Pragma("unroll") for (int m = 0; m < 4; ++m)                   \
      SA[m] = *(const i32x4*)&Ab[(RG) * 32768 + aBase + m * 2048 + (KX)]; \
    _Pragma("unroll") for (int n = 0; n < 4; ++n)                   \
      SB[n] = *(const i32x4*)&Bb[(RG) * 16384 + bBase + n * 2048 + (KX)]; } while (0)

#define G1_MFMA(SA, SB) do { __builtin_amdgcn_s_setprio(1);         \
    _Pragma("unroll") for (int m = 0; m < 4; ++m)                   \
      _Pragma("unroll") for (int n = 0; n < 4; ++n)                 \
        acc[m][n] = __builtin_amdgcn_mfma_i32_16x16x64_i8(SA[m], SB[n], acc[m][n], 0, 0, 0); \
    __builtin_amdgcn_s_setprio(0); } while (0)

__global__ __launch_bounds__(512) void k_gemm_gu(
    const i8* __restrict__ xq,      // [T][1024] i8
    const i8* __restrict__ wguq,    // [NE][1024][1024] i8 (B^T, gate/up interleaved)
    const int* __restrict__ seg, const int* __restrict__ segcnt,
    const int* __restrict__ btok, const float* __restrict__ sxg,
    const int* __restrict__ wam,
    u16* __restrict__ act)          // [NSLOT][ISZ] bf16
{
  const int bid = blockIdx.x;
  const int brow = (bid % NROWB) * BM;
  const int bcol = (bid / NROWB) * 128;
  int e;
  if (!seg_lookup(seg, segcnt, brow, e)) return;

  __shared__ __align__(16) i8 Ab[3 * 32768];   // 96 KB
  __shared__ __align__(16) i8 Bb[3 * 16384];   // 48 KB
  __shared__ float sxl[BM];

  const int tid = threadIdx.x;
  const int w = tid >> 6, l = tid & 63;
  const int wm = w >> 1, wn = w & 1;           // 4M x 2N
  const int fr = l & 15, fg = l >> 4;

  if (tid < BM) {
    const int rrow = brow + tid;
    const int tk = (e < 8) ? btok[rrow] : (rrow - RBASE);
    sxl[tid] = sxg[tk];
  }

  const int rr = w * 8 + (l >> 3);
  const int sw = ((l & 7) ^ (l >> 3)) * 16;    // pre-swizzled 16B chunk (bytes)
  int tr[4];
#pragma unroll
  for (int j = 0; j < 4; ++j) {
    const int gr = brow + j * 64 + rr;
    tr[j] = (e < 8) ? btok[gr] : (gr - RBASE);
  }
  const i8* sA0 = xq + (size_t)tr[0] * HID + sw;
  const i8* sA1 = xq + (size_t)tr[1] * HID + sw;
  const i8* sA2 = xq + (size_t)tr[2] * HID + sw;
  const i8* sA3 = xq + (size_t)tr[3] * HID + sw;
  const i8* sB0 = wguq + ((size_t)e * 1024 + bcol + 0 * 64 + rr) * HID + sw;
  const i8* sB1 = wguq + ((size_t)e * 1024 + bcol + 1 * 64 + rr) * HID + sw;

  const int aBase = (wm * 64 + fr) * 128;      // bytes (128-B rows)
  const int bBase = (wn * 64 + fr) * 128;
  const int kx0 = (fg ^ (fr & 7)) * 16;
  const int kx1 = kx0 ^ 64;

  i32x4 acc[4][4];
#pragma unroll
  for (int m = 0; m < 4; ++m)
#pragma unroll
    for (int n = 0; n < 4; ++n) acc[m][n] = (i32x4){0, 0, 0, 0};
  i32x4 fA0[4], fB0[4], fA1[4], fB1[4];

  const int NKT = HID / 128;   // 8 slots
  G1_STG(0); G1_STG(1);
  asm volatile("s_waitcnt vmcnt(6)" ::: "memory");
  __builtin_amdgcn_s_barrier();
  for (int s = 0; s < NKT; ++s) {
    const int rg = s % 3;
    if (s + 2 < NKT) G1_STG(s + 2);
    G1_LOADF(fA0, fB0, rg, kx0);
    __builtin_amdgcn_sched_barrier(0);
    G1_LOADF(fA1, fB1, rg, kx1);
    asm volatile("s_waitcnt lgkmcnt(8)" ::: "memory");
    __builtin_amdgcn_sched_barrier(0);
    G1_MFMA(fA0, fB0);
    asm volatile("s_waitcnt lgkmcnt(0)" ::: "memory");
    __builtin_amdgcn_sched_barrier(0);
    G1_MFMA(fA1, fB1);
    if (s + 1 < NKT) {
      if (s + 2 < NKT) { asm volatile("s_waitcnt vmcnt(6)" ::: "memory"); }
      else             { asm volatile("s_waitcnt vmcnt(0)" ::: "memory"); }
      __builtin_amdgcn_s_barrier();
    }
  }

  const float swe = __int_as_float(wam[e]) * (1.f / 127.f);
#pragma unroll
  for (int m = 0; m < 4; ++m) {
#pragma unroll
    for (int p = 0; p < 2; ++p) {
      const i32x4 gI = acc[m][2 * p], uI = acc[m][2 * p + 1];
      const int col = ((bcol + wn * 64) >> 1) + p * 16 + fr;
#pragma unroll
      for (int r = 0; r < 4; ++r) {
        const int row_l = wm * 64 + m * 16 + fg * 4 + r;
        const float sc = sxl[row_l] * swe;
        const float gate = (float)gI[r] * sc;
        const float up   = (float)uI[r] * sc;
        const float sv = gate / (1.f + __expf(-gate));
        act[(size_t)(brow + row_l) * ISZ + col] = f2bf(sv * up);
      }
    }
  }
}

// =================================================================================
// GEMM2 (bf16, r10 structure): 256x256 tile, BK=32, 8 waves 2M x 4N (128x64).
// 3-ring LDS (96 KB), counted vmcnt(4), 2 phases / K-tile.
// =================================================================================

#define D_STGA(kt) do { const int _d = ((kt) % 3) * 8192 + w * 1024; \
    STAGE(dA0 + (kt) * 32, As + _d);                                 \
    STAGE(dA1 + (kt) * 32, As + _d + 512); } while (0)
#define D_STGB(kt) do { const int _d = ((kt) % 3) * 8192 + w * 1024; \
    STAGE(dB0 + (kt) * 32, Bs + _d);                                 \
    STAGE(dB1 + (kt) * 32, Bs + _d + 512); } while (0)
#define D_LDA4(sl, mb) do {                                          \
    af[0] = *(const short8*)&As[(sl) + aOff + ((mb) + 0) * 512];     \
    af[1] = *(const short8*)&As[(sl) + aOff + ((mb) + 1) * 512];     \
    af[2] = *(const short8*)&As[(sl) + aOff + ((mb) + 2) * 512];     \
    af[3] = *(const short8*)&As[(sl) + aOff + ((mb) + 3) * 512]; } while (0)
#define D_LDB4(sl) do {                                              \
    bf[0] = *(const short8*)&Bs[(sl) + bOff + 0 * 512];              \
    bf[1] = *(const short8*)&Bs[(sl) + bOff + 1 * 512];              \
    bf[2] = *(const short8*)&Bs[(sl) + bOff + 2 * 512];              \
    bf[3] = *(const short8*)&Bs[(sl) + bOff + 3 * 512]; } while (0)
#define D_MFMA16(mb) do { __builtin_amdgcn_s_setprio(1);             \
    _Pragma("unroll") for (int mm = 0; mm < 4; ++mm)                 \
      _Pragma("unroll") for (int nn = 0; nn < 4; ++nn)               \
        accf[(mb) + mm][nn] = __builtin_amdgcn_mfma_f32_16x16x32_bf16( \
            af[mm], bf[nn], accf[(mb) + mm][nn], 0, 0, 0);           \
    __builtin_amdgcn_s_setprio(0); } while (0)

__global__ __launch_bounds__(512) void k_gemm_down(
    const u16* __restrict__ act, const u16* __restrict__ wdT,
    const int* __restrict__ seg, const int* __restrict__ segcnt,
    u16* __restrict__ tmp) {
  const int brow = blockIdx.x * BM;
  const int bcol = blockIdx.y * 256;
  int e;
  if (!seg_lookup(seg, segcnt, brow, e)) return;

  __shared__ __align__(16) u16 As[3 * 8192];
  __shared__ __align__(16) u16 Bs[3 * 8192];

  const int tid = threadIdx.x;
  const int w = tid >> 6, l = tid & 63;
  const int wm = w >> 2, wn = w & 3;
  const int fr = l & 15, fg = l >> 4;

  const int arow0 = (w * 128 + l) >> 2;
  const int swd = ((l & 3) ^ (arow0 & 3)) * 8;
  const u16* dA0 = act + (size_t)(brow + arow0) * ISZ + swd;
  const u16* dA1 = act + (size_t)(brow + arow0 + 16) * ISZ + swd;
  const u16* dB0 = wdT + ((size_t)e * 1024 + bcol + arow0) * ISZ + swd;
  const u16* dB1 = wdT + ((size_t)e * 1024 + bcol + arow0 + 16) * ISZ + swd;

  const int aOff = (wm * 128 + fr) * 32 + ((fg ^ (fr & 3)) * 8);
  const int bOff = (wn * 64 + fr) * 32 + ((fg ^ (fr & 3)) * 8);

  f32x4 accf[8][4];
#pragma unroll
  for (int m = 0; m < 8; ++m)
#pragma unroll
    for (int n = 0; n < 4; ++n) accf[m][n] = (f32x4){0.f, 0.f, 0.f, 0.f};
  short8 af[4], bf[4];

  const int NKT = ISZ / 32;   // 16
  D_STGA(0); D_STGB(0); D_STGA(1); D_STGB(1);
  asm volatile("s_waitcnt vmcnt(4)" ::: "memory");
  __builtin_amdgcn_s_barrier();
  for (int kt = 0; kt < NKT; ++kt) {
    const int sl = (kt % 3) * 8192;
    D_LDA4(sl, 0); D_LDB4(sl);
    if (kt + 2 < NKT) D_STGA(kt + 2);
    __builtin_amdgcn_s_barrier();
    asm volatile("s_waitcnt lgkmcnt(0)" ::: "memory");
    __builtin_amdgcn_sched_barrier(0);
    D_MFMA16(0);
    __builtin_amdgcn_s_barrier();
    D_LDA4(sl, 4);
    if (kt + 2 < NKT) D_STGB(kt + 2);
    __builtin_amdgcn_s_barrier();
    asm volatile("s_waitcnt lgkmcnt(0)" ::: "memory");
    __builtin_amdgcn_sched_barrier(0);
    D_MFMA16(4);
    if (kt + 2 < NKT)      { asm volatile("s_waitcnt vmcnt(4)" ::: "memory"); }
    else if (kt + 1 < NKT) { asm volatile("s_waitcnt vmcnt(0)" ::: "memory"); }
    __builtin_amdgcn_s_barrier();
  }

#pragma unroll
  for (int m = 0; m < 8; ++m) {
#pragma unroll
    for (int r = 0; r < 4; ++r) {
      const int row = brow + wm * 128 + m * 16 + fg * 4 + r;
#pragma unroll
      for (int n = 0; n < 4; ++n) {
        const int col = bcol + wn * 64 + n * 16 + fr;
        tmp[(size_t)row * HID + col] = f2bf(accf[m][n][r]);
      }
    }
  }
}

// ---------------- combine: out[t] = tmp[sh] + w0*tmp[s0] + w1*tmp[s1] -----------
__global__ __launch_bounds__(256) void k_combine(
    const u16* __restrict__ tmp, const int* __restrict__ slotmap,
    const float2* __restrict__ wts, float* __restrict__ out) {
  const int idx = blockIdx.x * 256 + threadIdx.x;
  const int t = idx >> 7;
  const int c = (idx & 127) << 3;
  const int s0 = slotmap[2 * t], s1 = slotmap[2 * t + 1];
  const float2 wv = wts[t];
  const short8 a = *(const short8*)(tmp + (size_t)s0 * HID + c);
  const short8 b = *(const short8*)(tmp + (size_t)s1 * HID + c);
  const short8 s = *(const short8*)(tmp + (size_t)(RBASE + t) * HID + c);
  float r[8];
#pragma unroll
  for (int j = 0; j < 8; ++j)
    r[j] = bf2f((u16)s[j]) + wv.x * bf2f((u16)a[j]) + wv.y * bf2f((u16)b[j]);
  float* po = out + (size_t)t * HID + c;
  *(float4*)po       = make_float4(r[0], r[1], r[2], r[3]);
  *(float4*)(po + 4) = make_float4(r[4], r[5], r[6], r[7]);
}

// ---------------- launch ----------------
extern "C" void kernel_launch(void* const* d_in, const int* in_sizes, int n_in,
                              void* d_out, int out_size, void* d_ws, size_t ws_size,
                              hipStream_t stream) {
  const float* x   = (const float*)d_in[0];
  const float* wg  = (const float*)d_in[1];
  const float* wgu = (const float*)d_in[2];
  const float* wdn = (const float*)d_in[3];
  const float* wsg = (const float*)d_in[4];
  const float* wsd = (const float*)d_in[5];
  float* out = (float*)d_out;

  char* ws = (char*)d_ws;
  i8*  xq    = (i8*)ws;   ws += (size_t)T_TOK * HID;
  i8*  wguq  = (i8*)ws;   ws += (size_t)NE * 1024 * HID;
  u16* wdT   = (u16*)ws;  ws += (size_t)NE * HID * ISZ * 2;
  u16* actb  = (u16*)ws;  ws += (size_t)NSLOT * ISZ * 2;
  u16* tmp   = (u16*)ws;  ws += (size_t)NSLOT * HID * 2;
  float* sxg = (float*)ws; ws += (size_t)T_TOK * 4;
  int* eidx  = (int*)ws;  ws += (size_t)T_TOK * 4;
  float2* wt = (float2*)ws; ws += (size_t)T_TOK * 8;
  int* btok  = (int*)ws;  ws += (size_t)RBASE * 4;
  int* smap  = (int*)ws;  ws += (size_t)2 * T_TOK * 4;
  int* seg   = (int*)ws;  ws += 16 * 4;
  int* segc  = (int*)ws;  ws += 16 * 4;
  int* wam   = (int*)ws;

  k_zero<<<1, 64, 0, stream>>>(wam);
  k_wamax<<<dim3(16, NE), 256, 0, stream>>>(wgu, wsg, wam);
  k_prep<<<NB_WGUP + NB_WDN + NB_RTR, 256, 0, stream>>>(
      x, wg, wgu, wsg, wdn, wsd, wam, xq, sxg, wguq, wdT, eidx, wt);
  k_scatter<<<1, 512, 0, stream>>>(eidx, btok, smap, seg, segc);
  k_gemm_gu<<<NROWB * 8, 512, 0, stream>>>(
      xq, wguq, seg, segc, btok, sxg, wam, actb);
  k_gemm_down<<<dim3(NROWB, HID / 256), 512, 0, stream>>>(actb, wdT, seg, segc, tmp);
  k_combine<<<(T_TOK * HID / 8) / 256, 256, 0, stream>>>(tmp, smap, wt, out);
}